// Round 8
// baseline (1112.947 us; speedup 1.0000x reference)
//
#include <hip/hip_runtime.h>

// FAVOR+ causal linear attention, fp32 I/O, bf16 MFMA chunked-GEMM,
// SINGLE fused kernel with decoupled-lookback chunk-prefix chaining.
// B=2, L=4096, H=8, D=64, M=128; 1024 chunks of T=64; 512 blocks x 2 chunks.
// Per block (ticket tk: bh = tk&15, g = tk>>4, chunks c=2g,2g+1):
//   1) stage V^T, compute Qf (A-frag regs) + Kf ([t][m] LDS) + Kft (scratch),
//      KV-partial MFMA (C-regs) + ks (shuffle) -- per chunk, all parallel.
//   2) wait flag(bh,g-1) [acquire, agent]; publish inclusive records
//      rec[c] = rec[c-1] + partial (linear coalesced bf16x8); flag release.
//   3) outputs: num = Qf*KVexcl + mask(Qf Kf^T)*V; den = Qf*ksexcl + rowsum.
// Ticket order makes the spin chain deadlock-free (pred always started first);
// 512 blocks @2/CU are fully co-resident anyway. Only 17MB of records hit HBM.

#define B_ 2
#define L_ 4096
#define H_ 8
#define D_ 64
#define M_ 128
#define BH_ 16
#define HD_ 512
#define LHD_ (L_*HD_)
#define C_ 64
#define T_ 64
#define RATIO 0.08838834764831845f
#define EPS 1e-3f

#define REC 8320               // shorts per record: 64*128 KV + 128 ks
#define REC_BASE 8192          // shorts; ctrl area = first 16 KB of ws
#define NBLK 512
#define VT_S 72                // [d][t]/[m][t]/Sm stride (shorts)
#define KF_S 136               // [t][m]/[d][m] stride (shorts)
#define SMEM_BYTES 74784

typedef __attribute__((ext_vector_type(8))) short bf16x8;
typedef __attribute__((ext_vector_type(4))) float f32x4;

__device__ __forceinline__ short f2bf(float f) {
  union { float f; unsigned u; } x; x.f = f;
  unsigned r = (x.u + 0x7fffu + ((x.u >> 16) & 1u)) >> 16;
  return (short)r;
}
__device__ __forceinline__ float bf2f(short s) {
  union { unsigned u; float f; } x; x.u = ((unsigned)(unsigned short)s) << 16;
  return x.f;
}
__device__ __forceinline__ bf16x8 load_cvt8(const float* p) {
  float4 a = *(const float4*)p;
  float4 b = *(const float4*)(p + 4);
  union { bf16x8 v; short s[8]; } u;
  u.s[0]=f2bf(a.x); u.s[1]=f2bf(a.y); u.s[2]=f2bf(a.z); u.s[3]=f2bf(a.w);
  u.s[4]=f2bf(b.x); u.s[5]=f2bf(b.y); u.s[6]=f2bf(b.z); u.s[7]=f2bf(b.w);
  return u.v;
}
#define MFMA(a,b,c) __builtin_amdgcn_mfma_f32_16x16x32_bf16((a),(b),(c),0,0,0)

__global__ __launch_bounds__(256) void initctl(int* __restrict__ ctrl) {
  for (int i = threadIdx.x; i < 2048; i += 256) ctrl[i] = 0;
}

__global__ __launch_bounds__(256, 2) void fused(
    const float* __restrict__ qq, const float* __restrict__ kk,
    const float* __restrict__ vv, const float* __restrict__ P,
    unsigned short* __restrict__ ws, float* __restrict__ out)
{
  extern __shared__ short smem[];
  short* VtL[2]; VtL[0] = smem;          VtL[1] = smem + 4608;     // [d][t] x2
  short* KfL[2]; KfL[0] = smem + 9216;   KfL[1] = smem + 17920;    // [t][m] x2
  short* Scr = smem + 26624;                                       // 9216 shorts
  float* ksp = (float*)(smem + 35840);                             // [4][128]
  float* ksA = ksp + 512;                                          // [128]
  float* ksB = ksA + 128;                                          // [128]
  int*   tkS = (int*)(ksB + 128);

  int* ctrl = (int*)ws;                        // [0]=ticket, [64..575]=flags
  unsigned short* recs = ws + REC_BASE;

  const int tid = threadIdx.x, w = tid >> 6, quad = (tid >> 4) & 3, l15 = tid & 15;
  if (tid == 0) *tkS = atomicAdd(&ctrl[0], 1);
  __syncthreads();
  const int tk = *tkS;
  const int bh = tk & 15, g = tk >> 4;
  const size_t gbase = (size_t)(bh >> 3)*LHD_ + (size_t)(bh & 7)*D_;
  const int cid0 = bh*C_ + 2*g;

  bf16x8 qfr[2][4];
  f32x4  pC[2][8];

  // ---------- phase 1: per-chunk features + partial sums ----------
  for (int s = 0; s < 2; ++s) {
    short* Vt = VtL[s];
    short* Kf = KfL[s];
    float* ksX = s ? ksB : ksA;
    const int t0 = (2*g + s)*T_;

    for (int fi = tid; fi < 64*16; fi += 256) {          // stage V^T
      int t = fi >> 4, d4 = (fi & 15)*4;
      float4 v4 = *(const float4*)(vv + gbase + (size_t)(t0+t)*HD_ + d4);
      Vt[(d4+0)*VT_S + t] = f2bf(v4.x);
      Vt[(d4+1)*VT_S + t] = f2bf(v4.y);
      Vt[(d4+2)*VT_S + t] = f2bf(v4.z);
      Vt[(d4+3)*VT_S + t] = f2bf(v4.w);
    }

    const float* qrow = qq + gbase + (size_t)(t0 + 16*w + l15)*HD_;
    const float* krow = kk + gbase + (size_t)(t0 + 16*w + l15)*HD_;
    bf16x8 aq0 = load_cvt8(qrow + quad*8);
    bf16x8 aq1 = load_cvt8(qrow + 32 + quad*8);
    bf16x8 ak0 = load_cvt8(krow + quad*8);
    bf16x8 ak1 = load_cvt8(krow + 32 + quad*8);
    f32x4 kasave[8];
    #pragma unroll
    for (int ct = 0; ct < 8; ++ct) {
      const float* prow = P + (ct*16 + l15)*64;
      bf16x8 bp0 = load_cvt8(prow + quad*8);
      bf16x8 bp1 = load_cvt8(prow + 32 + quad*8);
      f32x4 qa = {0.f,0.f,0.f,0.f}, ka = {0.f,0.f,0.f,0.f};
      qa = MFMA(aq0,bp0,qa); qa = MFMA(aq1,bp1,qa);
      ka = MFMA(ak0,bp0,ka); ka = MFMA(ak1,bp1,ka);
      kasave[ct] = ka;
      float ssum = 0.f;
      #pragma unroll
      for (int reg = 0; reg < 4; ++reg) {
        int trow = 16*w + 4*quad + reg, m = 16*ct + l15;
        float qv = fmaxf(qa[reg]*RATIO, 0.f) + EPS;
        float kv = fmaxf(ka[reg]*RATIO, 0.f) + EPS;
        Scr[trow*KF_S + m] = f2bf(qv);      // Qf bounce (own-wave rows)
        Kf [trow*KF_S + m] = f2bf(kv);      // persistent Kf [t][m]
        ssum += kv;
      }
      ssum += __shfl_xor(ssum, 16);
      ssum += __shfl_xor(ssum, 32);
      if (quad == 0) ksp[w*128 + 16*ct + l15] = ssum;
    }
    #pragma unroll
    for (int k2 = 0; k2 < 4; ++k2)          // own-wave rows, pre-barrier OK
      qfr[s][k2] = *(const bf16x8*)&Scr[(16*w + l15)*KF_S + k2*32 + quad*8];
    __syncthreads();                        // Qf reads done; Vt/ksp complete

    if (tid < 128)
      ksX[tid] = ksp[tid] + ksp[128+tid] + ksp[256+tid] + ksp[384+tid];
    #pragma unroll
    for (int ct = 0; ct < 8; ++ct)          // Kft [m][t] into Scr
      #pragma unroll
      for (int reg = 0; reg < 4; ++reg)
        Scr[(16*ct + l15)*VT_S + 16*w + 4*quad + reg] =
            f2bf(fmaxf(kasave[ct][reg]*RATIO, 0.f) + EPS);
    __syncthreads();                        // Kft ready

    bf16x8 av0 = *(const bf16x8*)&Vt[(16*w + l15)*VT_S + quad*8];
    bf16x8 av1 = *(const bf16x8*)&Vt[(16*w + l15)*VT_S + 32 + quad*8];
    #pragma unroll
    for (int mt = 0; mt < 8; ++mt) {        // KV-partial, C-regs
      f32x4 acc = {0.f,0.f,0.f,0.f};
      bf16x8 b0 = *(const bf16x8*)&Scr[(16*mt + l15)*VT_S + quad*8];
      bf16x8 b1 = *(const bf16x8*)&Scr[(16*mt + l15)*VT_S + 32 + quad*8];
      acc = MFMA(av0, b0, acc);
      acc = MFMA(av1, b1, acc);
      pC[s][mt] = acc;
    }
    __syncthreads();                        // Scr free for next chunk
  }

  // ---------- phase 2: lookback + publish inclusive records ----------
  unsigned short* rec0 = recs + (size_t)cid0*REC;
  unsigned short* rec1 = rec0 + REC;
  const unsigned short* predR = recs + (size_t)(cid0-1)*REC;
  const int hasPred = (g > 0);

  // bounce p0 C-regs -> Scr [d][m] (stride KF_S)
  #pragma unroll
  for (int mt = 0; mt < 8; ++mt)
    #pragma unroll
    for (int reg = 0; reg < 4; ++reg)
      Scr[(16*w + 4*quad + reg)*KF_S + 16*mt + l15] = f2bf(pC[0][mt][reg]);
  __syncthreads();

  if (hasPred) {
    if (tid == 0) {
      while (__hip_atomic_load(&ctrl[64 + bh*32 + g - 1],
                               __ATOMIC_ACQUIRE, __HIP_MEMORY_SCOPE_AGENT) == 0)
        __builtin_amdgcn_s_sleep(1);
    }
    __syncthreads();
  }

  float keep[32];                            // incl0 KV values (fp32)
  #pragma unroll
  for (int jj = 0; jj < 4; ++jj) {
    int j = tid + jj*256;                    // group of 8 shorts, 0..1023
    int d = j >> 4, part = j & 15;
    bf16x8 p = *(const bf16x8*)&Scr[d*KF_S + part*8];
    bf16x8 pr;
    if (hasPred) pr = *(const bf16x8*)(predR + j*8);
    union { bf16x8 v; short s[8]; } o;
    #pragma unroll
    for (int i = 0; i < 8; ++i) {
      float v = bf2f(p[i]) + (hasPred ? bf2f(pr[i]) : 0.f);
      keep[jj*8+i] = v;
      o.s[i] = f2bf(v);
    }
    *(bf16x8*)(rec0 + j*8) = o.v;
  }
  float kks = 0.f;
  if (tid < 128) {
    kks = ksA[tid] + (hasPred ? bf2f((short)predR[8192 + tid]) : 0.f);
    rec0[8192 + tid] = (unsigned short)f2bf(kks);
  }
  __syncthreads();                           // Scr free
  #pragma unroll
  for (int mt = 0; mt < 8; ++mt)             // bounce p1
    #pragma unroll
    for (int reg = 0; reg < 4; ++reg)
      Scr[(16*w + 4*quad + reg)*KF_S + 16*mt + l15] = f2bf(pC[1][mt][reg]);
  __syncthreads();
  #pragma unroll
  for (int jj = 0; jj < 4; ++jj) {
    int j = tid + jj*256;
    int d = j >> 4, part = j & 15;
    bf16x8 p = *(const bf16x8*)&Scr[d*KF_S + part*8];
    union { bf16x8 v; short s[8]; } o;
    #pragma unroll
    for (int i = 0; i < 8; ++i) o.s[i] = f2bf(keep[jj*8+i] + bf2f(p[i]));
    *(bf16x8*)(rec1 + j*8) = o.v;
  }
  if (tid < 128) rec1[8192 + tid] = (unsigned short)f2bf(kks + ksB[tid]);
  __threadfence();
  __syncthreads();
  if (tid == 0)
    __hip_atomic_store(&ctrl[64 + bh*32 + g], 1,
                       __ATOMIC_RELEASE, __HIP_MEMORY_SCOPE_AGENT);
  __syncthreads();                           // Scr free for Sm

  // ---------- phase 3: outputs ----------
  for (int s = 0; s < 2; ++s) {
    const int t0 = (2*g + s)*T_;
    const int hp = hasPred || (s == 1);
    const unsigned short* pr = recs + (size_t)(cid0 + s - 1)*REC;
    const short* Kf = KfL[s];
    const short* Vt = VtL[s];

    bf16x8* qf = qfr[s];
    float dp = 0.f;
    if (hp) {
      #pragma unroll
      for (int k2 = 0; k2 < 4; ++k2) {
        bf16x8 kv8 = *(const bf16x8*)(pr + 8192 + k2*32 + quad*8);
        #pragma unroll
        for (int j = 0; j < 8; ++j) dp += bf2f(qf[k2][j]) * bf2f(kv8[j]);
      }
      dp += __shfl_xor(dp, 16);
      dp += __shfl_xor(dp, 32);
    }

    f32x4 nacc[4];
    #pragma unroll
    for (int ct = 0; ct < 4; ++ct) { f32x4 z = {0.f,0.f,0.f,0.f}; nacc[ct] = z; }
    if (hp) {
      #pragma unroll
      for (int k2 = 0; k2 < 4; ++k2)
        #pragma unroll
        for (int ct = 0; ct < 4; ++ct) {
          bf16x8 bb = *(const bf16x8*)(pr + (16*ct + l15)*128 + k2*32 + quad*8);
          nacc[ct] = MFMA(qf[k2], bb, nacc[ct]);
        }
    }

    f32x4 sacc[4];
    #pragma unroll
    for (int jt = 0; jt < 4; ++jt) { f32x4 z = {0.f,0.f,0.f,0.f}; sacc[jt] = z; }
    #pragma unroll
    for (int k2 = 0; k2 < 4; ++k2)
      #pragma unroll
      for (int jt = 0; jt < 4; ++jt) {
        bf16x8 bb = *(const bf16x8*)&Kf[(16*jt + l15)*KF_S + k2*32 + quad*8];
        sacc[jt] = MFMA(qf[k2], bb, sacc[jt]);
      }
    float rs[4] = {0.f,0.f,0.f,0.f};
    #pragma unroll
    for (int jt = 0; jt < 4; ++jt)
      #pragma unroll
      for (int reg = 0; reg < 4; ++reg) {
        int row = 16*w + 4*quad + reg, j = 16*jt + l15;
        float val = (j <= row) ? sacc[jt][reg] : 0.f;
        rs[reg] += val;
        Scr[row*VT_S + j] = f2bf(val);       // Sm, own-wave rows
      }
    #pragma unroll
    for (int reg = 0; reg < 4; ++reg) {
      rs[reg] += __shfl_xor(rs[reg], 1);
      rs[reg] += __shfl_xor(rs[reg], 2);
      rs[reg] += __shfl_xor(rs[reg], 4);
      rs[reg] += __shfl_xor(rs[reg], 8);
    }
    #pragma unroll
    for (int kx = 0; kx < 2; ++kx) {
      bf16x8 a = *(const bf16x8*)&Scr[(16*w + l15)*VT_S + kx*32 + quad*8];
      #pragma unroll
      for (int ct = 0; ct < 4; ++ct) {
        bf16x8 bb = *(const bf16x8*)&Vt[(16*ct + l15)*VT_S + kx*32 + quad*8];
        nacc[ct] = MFMA(a, bb, nacc[ct]);
      }
    }
    #pragma unroll
    for (int reg = 0; reg < 4; ++reg) {
      float den1 = __shfl(dp, 4*quad + reg);
      float inv = 1.f / (den1 + rs[reg]);
      int trow = t0 + 16*w + 4*quad + reg;
      #pragma unroll
      for (int ct = 0; ct < 4; ++ct)
        out[gbase + (size_t)trow*HD_ + 16*ct + l15] = nacc[ct][reg] * inv;
    }
  }
}

extern "C" void kernel_launch(void* const* d_in, const int* in_sizes, int n_in,
                              void* d_out, int out_size, void* d_ws, size_t ws_size,
                              hipStream_t stream) {
  const float* q = (const float*)d_in[0];
  const float* k = (const float*)d_in[1];
  const float* v = (const float*)d_in[2];
  const float* P = (const float*)d_in[3];
  float* out = (float*)d_out;
  unsigned short* ws = (unsigned short*)d_ws;   // 16 KB ctrl + 17 MB records

  static bool attr_set = false;                 // host-side only; harmless
  if (!attr_set) {
    hipFuncSetAttribute((const void*)fused,
                        hipFuncAttributeMaxDynamicSharedMemorySize, SMEM_BYTES);
    attr_set = true;
  }
  initctl<<<dim3(1), dim3(256), 0, stream>>>((int*)ws);
  fused<<<dim3(NBLK), dim3(256), SMEM_BYTES, stream>>>(q, k, v, P, ws, out);
}